// Round 7
// baseline (263.790 us; speedup 1.0000x reference)
//
#include <hip/hip_runtime.h>

typedef __bf16 bf16x8 __attribute__((ext_vector_type(8)));
typedef __bf16 bf16x4 __attribute__((ext_vector_type(4)));
typedef float f32x4 __attribute__((ext_vector_type(4)));

typedef const __attribute__((address_space(1))) void* gptr_t;
typedef __attribute__((address_space(3))) void* lptr_t;

__device__ __forceinline__ f32x4 mfma16(bf16x8 a, bf16x8 b, f32x4 c) {
  return __builtin_amdgcn_mfma_f32_16x16x32_bf16(a, b, c, 0, 0, 0);
}

__device__ __forceinline__ void load_lds16(const __bf16* g, __bf16* l) {
  __builtin_amdgcn_global_load_lds((gptr_t)g, (lptr_t)l, 16, 0, 0);
}

__device__ __forceinline__ float fast_exp2(float x) {
#if __has_builtin(__builtin_amdgcn_exp2f)
  return __builtin_amdgcn_exp2f(x);
#else
  return exp2f(x);
#endif
}

// round-to-nearest(+away) f32->bf16 x2, packed into one dword (f0 low)
__device__ __forceinline__ unsigned pack_bf16(float f0, float f1) {
  unsigned u0 = __builtin_bit_cast(unsigned, f0) + 0x8000u;
  unsigned u1 = __builtin_bit_cast(unsigned, f1) + 0x8000u;
  return __builtin_amdgcn_perm(u1, u0, 0x07060302);
}

__device__ __forceinline__ bf16x8 cvt8(float4 v0, float4 v1) {
  union { bf16x8 h; uint4 u; } r;
  r.u.x = pack_bf16(v0.x, v0.y);
  r.u.y = pack_bf16(v0.z, v0.w);
  r.u.z = pack_bf16(v1.x, v1.y);
  r.u.w = pack_bf16(v1.z, v1.w);
  return r.h;
}

// ---- fp32 -> bf16 pre-convert, weights only: qkv_w (1536 blks), out_w (512)
__global__ __launch_bounds__(256) void convert_w(
    const float* __restrict__ w1, const float* __restrict__ w2,
    __bf16* __restrict__ w1b, __bf16* __restrict__ w2b) {
  int bid = blockIdx.x;
  const float* src = bid < 1536 ? w1 : w2;
  __bf16* dst = bid < 1536 ? w1b : w2b;
  int base = bid < 1536 ? bid : bid - 1536;
  size_t off = (size_t)base * 2048 + threadIdx.x * 8;
  float4 v0 = *(const float4*)(src + off);
  float4 v1 = *(const float4*)(src + off + 4);
  *(bf16x8*)(dst + off) = cvt8(v0, v1);
}

// C[M][N] = A[M][K] @ B[N][K]^T + bias[N]; B bf16 via global_load_lds.
// A: fp32 (fused convert: fp32 loads + pack + ds_write, same swizzled LDS
// image) or bf16 (global_load_lds). 128x128 tile, BK=32, double-buffered,
// chunk-swizzled staging -> conflict-free ds_read_b128 fragments.
template <bool A_F32, bool C_BF16>
__global__ __launch_bounds__(256) void gemm_bt(
    const void* __restrict__ Av, const __bf16* __restrict__ B,
    const float* __restrict__ bias, void* __restrict__ Cv, int M, int N,
    int K, int qcols) {
  __shared__ __bf16 As[2][128 * 32];
  __shared__ __bf16 Bs[2][128 * 32];

  const int tid = threadIdx.x;
  const int wid = tid >> 6;
  const int lane = tid & 63;
  const int l15 = lane & 15;
  const int quad = lane >> 4;
  const int bm = blockIdx.y * 128;
  const int bn = blockIdx.x * 128;
  const int wm = (wid & 1) * 64;
  const int wn = (wid >> 1) * 64;

  // staging: lane l -> local row wid*16+(l>>2), global chunk (l&3)^((l>>3)&3)
  const int srow = wid * 16 + (lane >> 2);
  const int schunk = ((lane & 3) ^ ((lane >> 3) & 3)) * 8;
  const int ldsoff = wid * 16 * 32;  // wave-uniform (lane*16B implicit)
  // explicit ds_write targets for the fused-convert A path (same image)
  const int ast0 = srow * 32 + (lane & 3) * 8;
  const int ast1 = (srow + 64) * 32 + (lane & 3) * 8;
  // fragment-read chunk slot (loop-invariant)
  const int fsl = (quad ^ ((l15 >> 1) & 3)) * 8;

  const __bf16* gB = B + (size_t)(bn + srow) * K + schunk;
  const float* gAf = nullptr;
  const __bf16* gAh = nullptr;
  if constexpr (A_F32)
    gAf = (const float*)Av + (size_t)(bm + srow) * K + schunk;
  else
    gAh = (const __bf16*)Av + (size_t)(bm + srow) * K + schunk;

  f32x4 acc[4][4] = {};
  float4 ar[4];

  // stage iter 0
  if constexpr (A_F32) {
    ar[0] = *(const float4*)(gAf);
    ar[1] = *(const float4*)(gAf + 4);
    ar[2] = *(const float4*)(gAf + (size_t)64 * K);
    ar[3] = *(const float4*)(gAf + (size_t)64 * K + 4);
    *(bf16x8*)(&As[0][ast0]) = cvt8(ar[0], ar[1]);
    *(bf16x8*)(&As[0][ast1]) = cvt8(ar[2], ar[3]);
  } else {
    load_lds16(gAh, &As[0][ldsoff]);
    load_lds16(gAh + (size_t)64 * K, &As[0][64 * 32 + ldsoff]);
  }
  load_lds16(gB, &Bs[0][ldsoff]);
  load_lds16(gB + (size_t)64 * K, &Bs[0][64 * 32 + ldsoff]);

  const int niter = K >> 5;
  for (int it = 0; it < niter; ++it) {
    const int cur = it & 1;
    __syncthreads();  // A writes + B arrivals drained; old-buffer readers done
    const bool more = (it + 1 < niter);
    if (more) {
      int k0 = (it + 1) << 5;
      load_lds16(gB + k0, &Bs[1 - cur][ldsoff]);
      load_lds16(gB + k0 + (size_t)64 * K, &Bs[1 - cur][64 * 32 + ldsoff]);
      if constexpr (A_F32) {
        ar[0] = *(const float4*)(gAf + k0);
        ar[1] = *(const float4*)(gAf + k0 + 4);
        ar[2] = *(const float4*)(gAf + k0 + (size_t)64 * K);
        ar[3] = *(const float4*)(gAf + k0 + (size_t)64 * K + 4);
      } else {
        load_lds16(gAh + k0, &As[1 - cur][ldsoff]);
        load_lds16(gAh + k0 + (size_t)64 * K, &As[1 - cur][64 * 32 + ldsoff]);
      }
    }
    bf16x8 af[4], bf[4];
#pragma unroll
    for (int i = 0; i < 4; ++i)
      af[i] = *(const bf16x8*)(&As[cur][(wm + i * 16 + l15) * 32 + fsl]);
#pragma unroll
    for (int i = 0; i < 4; ++i)
      bf[i] = *(const bf16x8*)(&Bs[cur][(wn + i * 16 + l15) * 32 + fsl]);
#pragma unroll
    for (int mt = 0; mt < 4; ++mt)
#pragma unroll
      for (int nt = 0; nt < 4; ++nt)
        acc[mt][nt] = mfma16(af[mt], bf[nt], acc[mt][nt]);
    if constexpr (A_F32) {
      if (more) {  // write next A tile after this iter's fragment reads
        *(bf16x8*)(&As[1 - cur][ast0]) = cvt8(ar[0], ar[1]);
        *(bf16x8*)(&As[1 - cur][ast1]) = cvt8(ar[2], ar[3]);
      }
    }
  }

  const float sc = (bn < qcols) ? 0.18033688011112043f : 1.0f;
#pragma unroll
  for (int mt = 0; mt < 4; ++mt) {
#pragma unroll
    for (int nt = 0; nt < 4; ++nt) {
      int gc = bn + wn + nt * 16 + l15;
      float bv = bias[gc];
#pragma unroll
      for (int r = 0; r < 4; ++r) {
        int gr = bm + wm + mt * 16 + quad * 4 + r;
        float val = (acc[mt][nt][r] + bv) * sc;
        if constexpr (C_BF16)
          ((__bf16*)Cv)[(size_t)gr * N + gc] = (__bf16)val;
        else
          ((float*)Cv)[(size_t)gr * N + gc] = val;
      }
    }
  }
}

// exp + (optional causal mask) + deferred-l + packed P store in pi-layout.
template <bool MASK>
__device__ __forceinline__ void softmax_block(f32x4 (&s)[2][4],
                                              float (&lsum)[2][4],
                                              __bf16* __restrict__ psw,
                                              int kv0, int qrow_base, int quad,
                                              int l15) {
#pragma unroll
  for (int mt = 0; mt < 2; ++mt) {
#pragma unroll
    for (int r = 0; r < 4; ++r) {
      int prow = mt * 16 + quad * 4 + r;
      float p[4];
#pragma unroll
      for (int nt = 0; nt < 4; ++nt) {
        p[nt] = fast_exp2(s[mt][nt][r]);  // scale pre-folded into Q
        if constexpr (MASK) {
          if ((kv0 + nt * 16 + l15) > (qrow_base + prow)) p[nt] = 0.f;
        }
      }
      lsum[mt][r] += (p[0] + p[1]) + (p[2] + p[3]);
      uint2 w = {pack_bf16(p[0], p[1]), pack_bf16(p[2], p[3])};
      int o = ((l15 >> 1) ^ (prow & 7)) & 7;
      *(uint2*)(psw + prow * 64 + o * 8 + 4 * (l15 & 1)) = w;
    }
  }
}

// Flash attention, causal. qkv: (B*T, 3072) bf16 (Q pre-scaled by log2e/8);
// out: (B*T, 1024) bf16. Grid (64 bh, 16 qt) bh-fastest (KV L2-resident per
// XCD); q-tile = 15 - blockIdx.y -> longest blocks dispatch first (LPT
// schedule hides causal imbalance; 1024 blocks, ~3/CU resident).
// Block 256 = 4 waves, BQ=128, BKV=64. P/V k-index permuted by
// pi(k)=4*(k&15)+(k>>4); XOR octet swizzles; no-max softmax, deferred l.
__global__ __launch_bounds__(256) void attn_kernel(
    const __bf16* __restrict__ qkv, __bf16* __restrict__ out) {
  constexpr int T = 2048, C3 = 3072;
  constexpr int KVSTEP = 64 * C3;
  __shared__ __bf16 Ks[2][64 * 64];  // [kv][d]
  __shared__ __bf16 Vt[2][64 * 64];  // [d][pi(kv)]
  __shared__ __bf16 Ps[4][32 * 64];  // per-wave [qrow][pi(kv)]

  const int tid = threadIdx.x;
  const int wid = tid >> 6;
  const int lane = tid & 63;
  const int l15 = lane & 15;
  const int quad = lane >> 4;
  const int bh = blockIdx.x;           // 0..63 (fastest -> same XCD per bh)
  const int qp = 15 - blockIdx.y;      // longest-first
  const int b = bh >> 4, h = bh & 15;
  const size_t rowbase = (size_t)b * T;

  const int kr = tid >> 3;  // K staging: rows kr, kr+32
  const int kc = tid & 7;   // d-octet
  const int vj = tid >> 4;  // V staging: rows vj+16i -> pi-cols 4vj+i
  const int vn = tid & 15;  // d-nibble

  // ---- loop-invariant LDS offsets ----
  const int ks_st0 = kr * 64 + ((kc ^ (kr & 7)) * 8);
  const int ks_st1 = (kr + 32) * 64 + ((kc ^ ((kr + 32) & 7)) * 8);
  int vt_st[4];
#pragma unroll
  for (int dd = 0; dd < 4; ++dd) {
    int d = 4 * vn + dd;
    vt_st[dd] = d * 64 + ((((vj >> 1) ^ (d & 7) ^ (d >> 3)) & 7) * 8) +
                4 * (vj & 1);
  }
  int kf_off[4][2];
#pragma unroll
  for (int nt = 0; nt < 4; ++nt)
#pragma unroll
    for (int ksi = 0; ksi < 2; ++ksi)
      kf_off[nt][ksi] =
          (nt * 16 + l15) * 64 + (((4 * ksi + quad) ^ (l15 & 7)) * 8);
  int pf_off[2][2];
#pragma unroll
  for (int mt = 0; mt < 2; ++mt)
#pragma unroll
    for (int ksi = 0; ksi < 2; ++ksi)
      pf_off[mt][ksi] =
          (mt * 16 + l15) * 64 + (((4 * ksi + quad) ^ (l15 & 7)) * 8);
  int vf_off[4][2];
#pragma unroll
  for (int ntv = 0; ntv < 4; ++ntv)
#pragma unroll
    for (int ksi = 0; ksi < 2; ++ksi) {
      int d = ntv * 16 + l15;
      vf_off[ntv][ksi] =
          d * 64 + ((((4 * ksi + quad) ^ (d & 7) ^ (d >> 3)) & 7) * 8);
    }

  const int q0 = qp * 128;
  const int ntiles = 2 * qp + 2;
  const int qrow_base = q0 + wid * 32;

  bf16x8 qf[2][2];
#pragma unroll
  for (int mt = 0; mt < 2; ++mt)
#pragma unroll
    for (int ksi = 0; ksi < 2; ++ksi)
      qf[mt][ksi] = *(const bf16x8*)(
          qkv + (rowbase + qrow_base + mt * 16 + l15) * C3 + h * 64 +
          ksi * 32 + quad * 8);

  f32x4 acc[2][4] = {};
  float lsum[2][4] = {};

  const __bf16* gk = qkv + rowbase * C3 + 1024 + h * 64 + kr * C3 + kc * 8;
  const __bf16* gv = qkv + rowbase * C3 + 2048 + h * 64 + vj * C3 + vn * 4;

  bf16x8 kreg[2];
  bf16x4 vreg[4];
  kreg[0] = *(const bf16x8*)(gk);
  kreg[1] = *(const bf16x8*)(gk + 32 * C3);
#pragma unroll
  for (int i = 0; i < 4; ++i)
    vreg[i] = *(const bf16x4*)(gv + i * 16 * C3);

  for (int j = 0; j < ntiles; ++j) {
    __bf16* ksb = Ks[j & 1];
    __bf16* vtb = Vt[j & 1];
    *(bf16x8*)(ksb + ks_st0) = kreg[0];
    *(bf16x8*)(ksb + ks_st1) = kreg[1];
#pragma unroll
    for (int dd = 0; dd < 4; ++dd) {
      bf16x4 t = {vreg[0][dd], vreg[1][dd], vreg[2][dd], vreg[3][dd]};
      *(bf16x4*)(vtb + vt_st[dd]) = t;
    }
    if (j + 1 < ntiles) {
      gk += KVSTEP;
      gv += KVSTEP;
      kreg[0] = *(const bf16x8*)(gk);
      kreg[1] = *(const bf16x8*)(gk + 32 * C3);
#pragma unroll
      for (int i = 0; i < 4; ++i)
        vreg[i] = *(const bf16x4*)(gv + i * 16 * C3);
    }
    __syncthreads();

    const int kv0 = j * 64;
    // ---- S = Q K^T ----
    f32x4 s[2][4] = {};
#pragma unroll
    for (int nt = 0; nt < 4; ++nt) {
#pragma unroll
      for (int ksi = 0; ksi < 2; ++ksi) {
        bf16x8 kf = *(const bf16x8*)(ksb + kf_off[nt][ksi]);
#pragma unroll
        for (int mt = 0; mt < 2; ++mt)
          s[mt][nt] = mfma16(qf[mt][ksi], kf, s[mt][nt]);
      }
    }
    // ---- softmax (wave-uniform mask branch) ----
    if ((kv0 + 63) > qrow_base)
      softmax_block<true>(s, lsum, Ps[wid], kv0, qrow_base, quad, l15);
    else
      softmax_block<false>(s, lsum, Ps[wid], kv0, qrow_base, quad, l15);

    // ---- O += P V (per-wave Ps: no barrier) ----
#pragma unroll
    for (int ksi = 0; ksi < 2; ++ksi) {
      bf16x8 pf[2];
#pragma unroll
      for (int mt = 0; mt < 2; ++mt)
        pf[mt] = *(const bf16x8*)(Ps[wid] + pf_off[mt][ksi]);
#pragma unroll
      for (int ntv = 0; ntv < 4; ++ntv) {
        bf16x8 vf = *(const bf16x8*)(vtb + vf_off[ntv][ksi]);
#pragma unroll
        for (int mt = 0; mt < 2; ++mt)
          acc[mt][ntv] = mfma16(pf[mt], vf, acc[mt][ntv]);
      }
    }
    __syncthreads();  // all readers done before next store into this buffer
  }

  // ---- epilogue: reduce l, normalize, store ----
#pragma unroll
  for (int mt = 0; mt < 2; ++mt)
#pragma unroll
    for (int r = 0; r < 4; ++r) {
      float l = lsum[mt][r];
      l += __shfl_xor(l, 1);
      l += __shfl_xor(l, 2);
      l += __shfl_xor(l, 4);
      l += __shfl_xor(l, 8);
      float inv = 1.0f / l;
      int row = qrow_base + mt * 16 + quad * 4 + r;
      size_t ob = (rowbase + row) * 1024 + h * 64;
#pragma unroll
      for (int ntv = 0; ntv < 4; ++ntv)
        out[ob + ntv * 16 + l15] = (__bf16)(acc[mt][ntv][r] * inv);
    }
}

extern "C" void kernel_launch(void* const* d_in, const int* in_sizes, int n_in,
                              void* d_out, int out_size, void* d_ws,
                              size_t ws_size, hipStream_t stream) {
  const float* x = (const float*)d_in[0];
  const float* qkv_w = (const float*)d_in[1];
  const float* qkv_b = (const float*)d_in[2];
  const float* out_w = (const float*)d_in[3];
  const float* out_b = (const float*)d_in[4];
  float* out = (float*)d_out;

  __bf16* qkv_ws = (__bf16*)d_ws;                  // 8192*3072
  __bf16* attn_ws = qkv_ws + (size_t)8192 * 3072;  // 8192*1024
  __bf16* wqb = attn_ws + (size_t)8192 * 1024;     // 3072*1024
  __bf16* wob = wqb + (size_t)3072 * 1024;         // 1024*1024

  convert_w<<<2048, 256, 0, stream>>>(qkv_w, out_w, wqb, wob);
  gemm_bt<true, true><<<dim3(24, 64), 256, 0, stream>>>(
      x, wqb, qkv_b, qkv_ws, 8192, 3072, 1024, 1024);
  attn_kernel<<<dim3(64, 16), 256, 0, stream>>>(qkv_ws, attn_ws);
  gemm_bt<false, false><<<dim3(8, 64), 256, 0, stream>>>(
      attn_ws, wob, out_b, out, 8192, 1024, 1024, 0);
}